// Round 9
// baseline (766.500 us; speedup 1.0000x reference)
//
#include <hip/hip_runtime.h>

// ---------------- problem constants ----------------
#define BB 32
#define TT 720
#define CC 512
#define PHIST 30
#define PFUT 14
#define PLEN 24
#define HID 256
#define NBC (BB*CC)          // 16384 sequences
#define XNELEM (BB*TT*CC)    // 11796480
#define KSTEPS 9             // K aug: 256 h + 32 aug = 288
#define ROWB 640             // LDS bytes per seq row (576 + pad for XOR swizzle)

// ws layout (bytes)
#define OFF_BENC   0u           // ks-major: 9 ks * 48 tiles * 64 lanes * 16 B = 442368
#define OFF_BDEC   442368u
#define OFF_BHEAD  884736u      // 9*64*16 = 9216
#define OFF_BNIN   893952u      // 2 * 16 tiles * 64 lanes * 16 B = 32768 (enc, dec)
#define OFF_DFEAT  926720u      // 14*9*4 = 504 (padded 512)
#define OFF_FEAT   927232u      // 30*8*16384*2 = 7864320
#define OFF_LAST   8791552u     // 32*4*512*4 = 262144

typedef short bf16x8 __attribute__((ext_vector_type(8)));
typedef float f32x4 __attribute__((ext_vector_type(4)));

__device__ __forceinline__ unsigned short f2bf(float f){
  unsigned u = __float_as_uint(f);
  u = (u + 0x7fffu + ((u >> 16) & 1u)) >> 16;
  return (unsigned short)u;
}
__device__ __forceinline__ float bf2f(short s){
  return __uint_as_float(((unsigned)(unsigned short)s) << 16);
}
// fast gates: v_rcp_f32 + v_exp_f32 only
__device__ __forceinline__ float sigm(float x){
  return __builtin_amdgcn_rcpf(1.f + __builtin_amdgcn_exp2f(-1.44269504f*x));
}
__device__ __forceinline__ float tanh_f(float x){
  return 1.f - 2.f*__builtin_amdgcn_rcpf(1.f + __builtin_amdgcn_exp2f(2.88539008f*x));
}

// h-column K-permutation: k = wv*32 + lr*2 + jt  <->  n = wv*32 + jt*16 + lr
__device__ __forceinline__ int nh_of_k(int k){
  return (k & 0xE0) | ((k & 1) << 4) | ((k >> 1) & 15);
}

// ---------------- prep: pack weights into MFMA B-fragment order ----------------
// Benc/Bdec ks-major: [ks][tile(=wv*6+t6)][lane][8 bf16]  (UNCHANGED layout)
__global__ void prep_kernel(
    const float* __restrict__ eWih, const float* __restrict__ eWhh,
    const float* __restrict__ ebih, const float* __restrict__ ebhh,
    const float* __restrict__ dWih, const float* __restrict__ dWhh,
    const float* __restrict__ dbih, const float* __restrict__ dbhh,
    const float* __restrict__ femb, const float* __restrict__ headW,
    const float* __restrict__ headb,
    unsigned short* __restrict__ Benc, unsigned short* __restrict__ Bdec,
    unsigned short* __restrict__ Bhead, unsigned short* __restrict__ Bnin,
    unsigned* __restrict__ dfeat)
{
  const int NE = 48*9*64; // 27648
  int id = blockIdx.x*256 + threadIdx.x;
  if (id < 2*NE){
    bool isenc = id < NE;
    int s = isenc ? id : id - NE;
    int g = s / 576, rem = s % 576, ks = rem / 64, lane = rem % 64;
    int wv = g / 6, t6 = g % 6;
    int n = (t6 >> 1)*256 + wv*32 + (t6 & 1)*16 + (lane & 15);
    int kb = ks*32 + (lane >> 4)*8;
    unsigned short* outp = (isenc ? Benc : Bdec) + ((size_t)((ks*48 + g)*64 + lane))*8;
    const float* Whh = isenc ? eWhh : dWhh;
    const float* Wih = isenc ? eWih : dWih;
    const float* bih = isenc ? ebih : dbih;
    const float* bhh = isenc ? ebhh : dbhh;
    const int FN = isenc ? 7 : 16;
    const int KC = 256 + FN;
    for (int e = 0; e < 8; ++e){
      int k = kb + e;
      float v;
      if (k < 256)            v = Whh[n*256 + nh_of_k(k)];
      else if (n < 512){      // r,z gates: input part + fused bias column
        if (k < KC)           v = Wih[n*FN + (k - 256)];
        else if (k == KC)     v = bih[n] + bhh[n];
        else                  v = 0.f;
      } else {                // n gate: only hidden bias (input part in Bnin)
        v = (k == KC) ? bhh[n] : 0.f;
      }
      outp[e] = f2bf(v);
    }
  } else if (id < 2*NE + 576){
    int s = id - 2*NE;
    int ks = s / 64, lane = s % 64;
    int o = lane & 15, kb = ks*32 + (lane >> 4)*8;
    unsigned short* outp = Bhead + (size_t)s*8;
    for (int e = 0; e < 8; ++e){
      int k = kb + e;
      float v = 0.f;
      if (o < 4){
        if (k < 256)       v = headW[o*256 + nh_of_k(k)];
        else if (k == 272) v = headb[o];
      }
      outp[e] = f2bf(v);
    }
  } else if (id < 2*NE + 576 + 2048){
    // Bnin: i_n input-part tiles, [enc/dec][tile=wv*2+jt][lane]
    int s3 = id - (2*NE + 576);
    int ed = s3 >> 10, rem = s3 & 1023;
    int wv = rem >> 7, jt = (rem >> 6) & 1, lane = rem & 63;
    int n = 512 + wv*32 + jt*16 + (lane & 15);
    unsigned short* outp = Bnin + (size_t)ed*8192 + (size_t)(((wv*2 + jt)*64) + lane)*8;
    const int FN = ed ? 16 : 7;
    const float* Wih = ed ? dWih : eWih;
    const float* bih = ed ? dbih : ebih;
    for (int e = 0; e < 8; ++e){
      int kk = (lane >> 4)*8 + e;
      float v;
      if (kk < FN)       v = Wih[n*FN + kk];
      else if (kk == FN) v = bih[n];
      else               v = 0.f;
      outp[e] = f2bf(v);
    }
  } else if (id < 2*NE + 576 + 2048 + PFUT*9){
    int s2 = id - (2*NE + 576 + 2048);
    int st = s2 / 9, d = s2 % 9;
    unsigned v;
    if (d < 8) v = (unsigned)f2bf(femb[st*16 + 2*d]) | ((unsigned)f2bf(femb[st*16 + 2*d + 1]) << 16);
    else       v = (unsigned)f2bf(1.0f);
    dfeat[s2] = v;
  }
}

// ---------------- stage A: SWT + stats + features + x_norm ----------------
__global__ __launch_bounds__(128,4) void stage_a_kernel(
    const float* __restrict__ x, float* __restrict__ xnorm,
    unsigned short* __restrict__ feat2, float* __restrict__ last_g)
{
  __shared__ float sG[2][2][64];
  const int tid = threadIdx.x, lane = tid & 63, half = tid >> 6;
  const int bc = blockIdx.x*64 + lane;
  const int b = bc >> 9, c = bc & 511;
  const float* xp = x + (size_t)b*TT*CC + c;
  float* op = xnorm + (size_t)b*TT*CC + c;
  float gsum = 0.f, gss = 0.f;
  float lastv[4] = {0,0,0,0};
  const float inv24 = 1.f/24.f, inv23 = 1.f/23.f;
  const int p0 = half*15, p1 = p0 + 15;

  for (int p = p0; p < p1; ++p){
    const int t0 = p*PLEN;
    float xl[31];
#pragma unroll
    for (int i = 0; i < 31; ++i){
      int t = t0 - 4 + i;
      t = (t < 0) ? -t : ((t >= TT) ? (2*TT - 2 - t) : t);
      xl[i] = xp[(size_t)t*CC];
    }
    float a1l[30];
#pragma unroll
    for (int j = 0; j < 30; ++j) a1l[j] = 0.5f*(xl[j] + xl[j+1]);
    if (p == 0){ a1l[2] = a1l[4]; a1l[1] = a1l[5]; a1l[0] = a1l[6]; }
    if (p == PHIST-1){ a1l[27] = a1l[25]; a1l[28] = a1l[24]; a1l[29] = a1l[23]; }
    float a2l[28];
#pragma unroll
    for (int m = 0; m < 28; ++m) a2l[m] = 0.5f*(a1l[m] + a1l[m+2]);
    if (p == 0){ a2l[1] = a2l[3]; a2l[0] = a2l[4]; }
    if (p == PHIST-1){ a2l[26] = a2l[24]; a2l[27] = a2l[23]; }
    float a3l[24], d1l[24], d2l[24], d3l[24];
    float sL=0, sL2=0, s2=0, s22=0, s3=0, s32=0, sH2=0;
#pragma unroll
    for (int n = 0; n < 24; ++n){
      float a3 = 0.5f*(a2l[n] + a2l[n+4]);
      float d1 = xl[n+4] - a1l[n+3];
      float d2 = a1l[n+3] - a2l[n+2];
      float d3 = a2l[n+2] - a3;
      a3l[n]=a3; d1l[n]=d1; d2l[n]=d2; d3l[n]=d3;
      sL += a3; sL2 += a3*a3;
      s2 += d2; s22 += d2*d2;
      s3 += d3; s32 += d3*d3;
      sH2 += d1*d1;
      gsum += a3; gss += a3*a3;
    }
    float mu   = sL*inv24;
    float sigL = fmaxf(sqrtf(fmaxf((sL2 - sL*sL*inv24)*inv23, 0.f)), 1e-3f);
    float sig2 = fmaxf(sqrtf(fmaxf((s22 - s2*s2*inv24)*inv23, 0.f)), 1e-3f);
    float sig3 = fmaxf(sqrtf(fmaxf((s32 - s3*s3*inv24)*inv23, 0.f)), 1e-3f);
    float EL = sL2*inv24, E2 = s22*inv24, E3 = s32*inv24, EH = sH2*inv24;
    float rho = EH / (EL + EH + E2 + E3 + 1e-6f);
    float lsl = __logf(sigL), ls2 = __logf(sig2), ls3 = __logf(sig3);
    size_t fb = ((size_t)p*8)*NBC + bc;
    feat2[fb + 0*NBC] = f2bf(mu);
    feat2[fb + 1*NBC] = f2bf(lsl);
    feat2[fb + 2*NBC] = f2bf(ls2);
    feat2[fb + 3*NBC] = f2bf(ls3);
    feat2[fb + 4*NBC] = f2bf(rho);
    if (p == PHIST-1){ lastv[0]=mu; lastv[1]=lsl; lastv[2]=ls2; lastv[3]=ls3; }
    float iL = 1.f/sigL, i2 = 1.f/sig2, i3 = 1.f/sig3;
#pragma unroll
    for (int n = 0; n < 24; ++n){
      float v = (a3l[n]-mu)*iL + d1l[n] + d2l[n]*i2 + d3l[n]*i3;
      op[(size_t)(t0+n)*CC] = v;
    }
  }
  sG[half][0][lane] = gsum; sG[half][1][lane] = gss;
  __syncthreads();
  float gs = sG[0][0][lane] + sG[1][0][lane];
  float g2 = sG[0][1][lane] + sG[1][1][lane];
  float mug  = gs*(1.f/720.f);
  float sigg = fmaxf(sqrtf(fmaxf((g2 - gs*gs*(1.f/720.f))*(1.f/719.f), 0.f)), 1e-3f);
  unsigned short f5 = f2bf(mug), f6 = f2bf(__logf(sigg)), f7 = f2bf(1.0f);
  for (int p = p0; p < p1; ++p){
    size_t fb = ((size_t)p*8)*NBC + bc;
    feat2[fb + 5*NBC] = f5;
    feat2[fb + 6*NBC] = f6;
    feat2[fb + 7*NBC] = f7;
  }
  if (half == 1){
#pragma unroll
    for (int o = 0; o < 4; ++o) last_g[((size_t)b*4 + o)*CC + c] = lastv[o];
  }
}

// ---------------- GRU: encoder 30 + decoder 14 + fused head ----------------
// 256 blocks x 1024 threads (16 waves); 64 seqs/block. Each wave owns 16
// hidden cols x 3 gates -> acc 48 + accin 16 = 64 regs, target 4 waves/SIMD.
// B ring: 3 slots x 3 tiles (distance 2 ksteps; 9%3==0 -> static slots).
// A/h LDS double-buffered, ONE barrier/step. Fast gates. setprio on MFMA.
__global__ __launch_bounds__(1024) void gru_kernel(
    const unsigned char* __restrict__ BencB, const unsigned char* __restrict__ BdecB,
    const bf16x8* __restrict__ Bhead, const bf16x8* __restrict__ BninP,
    const unsigned* __restrict__ dfeat,       // [14][9] packed dec A-aug dwords
    const unsigned short* __restrict__ feat2, // [30][8][16384] bf16
    const float* __restrict__ last_g,         // [32][4][512]
    float* __restrict__ pred)                 // [32][14][4][512]
{
  __shared__ unsigned char Ab[2][64*ROWB];    // 2 x 40960
  const int tid = threadIdx.x;
  const int w = tid >> 6, l = tid & 63, lr = l & 15, lg = l >> 4;
  const int bc0 = blockIdx.x * 64;
  const int b = bc0 >> 9, c0 = bc0 & 511;

  for (int i = tid; i < 2*64*ROWB/4; i += 1024) ((unsigned*)Ab)[i] = 0u;

  // per-wave B base: tile (w>>1)*6 + (w&1); gates at +g*2048; ks at +49152
  const unsigned char* Bwe = BencB + (size_t)((((w>>1)*6 + (w&1))*64 + l))*16;
  const unsigned char* Bwd = BdecB + (size_t)((((w>>1)*6 + (w&1))*64 + l))*16;

  // i_n input-part tile (resident; swapped at decoder start). Old idx == w.
  bf16x8 bnin = BninP[(size_t)w*64 + l];

  // packed h state: this wave's col = w*16+lr; 16 seqs -> 8 packed u32
  unsigned hp[4][2];
#pragma unroll
  for (int m=0;m<4;m++){ hp[m][0]=0u; hp[m][1]=0u; }

  // h-write byte offset within row (k-permuted): k = (w>>1)*32 + lr*2 + (w&1)
  const int khw = (w>>1)*64 + lr*4 + (w&1)*2;

  // B ring: 3 slots x 3 gate-tiles; preload ks 0,1 of step 0
  bf16x8 bb[3][3];
#pragma unroll
  for (int g=0;g<3;g++){
    bb[0][g] = *(const bf16x8*)(Bwe + (size_t)g*2048);
    bb[1][g] = *(const bf16x8*)(Bwe + 49152 + (size_t)g*2048);
  }

  __syncthreads();
  { // stage encoder features for step 0 into parity 0
    int seq = tid & 63, f = tid >> 6;
    if (f < 8){
      unsigned short v = feat2[((size_t)0*8 + f)*NBC + bc0 + seq];
      *(unsigned short*)(Ab[0] + seq*ROWB + ((512 + f*2) ^ ((seq & 7) << 4))) = v;
    }
  }
  __syncthreads();

  for (int step = 0; step < PHIST + PFUT; ++step){
    const bool enc = step < PHIST;
    const int sp = step & 1;
    const unsigned char* A  = Ab[sp];
    unsigned char*       An = Ab[sp^1];
    const unsigned char* Bc = enc ? Bwe : Bwd;
    const unsigned char* Bn = (step == PHIST-1) ? Bwd :
                              ((step >= PHIST+PFUT-1) ? Bwe : Bc);
    if (step == PHIST) bnin = BninP[1024 + (size_t)w*64 + l];

    f32x4 acc[3][4];
    f32x4 accin[4];
#pragma unroll
    for (int g=0;g<3;g++)
#pragma unroll
      for (int m=0;m<4;m++) acc[g][m] = (f32x4){0.f,0.f,0.f,0.f};
#pragma unroll
    for (int m=0;m<4;m++) accin[m] = (f32x4){0.f,0.f,0.f,0.f};

#pragma unroll
    for (int ks = 0; ks < KSTEPS; ++ks){
      // prefetch kstep ks+2 into slot (ks+2)%3 (wraps into next step)
      {
        const int tk = ks + 2;
        const unsigned char* bp = (tk < KSTEPS) ? Bc : Bn;
        const int rk = (tk < KSTEPS) ? tk : tk - KSTEPS;
#pragma unroll
        for (int g = 0; g < 3; ++g)
          bb[tk % 3][g] = *(const bf16x8*)(bp + (size_t)rk*49152 + g*2048);
      }
      bf16x8 af[4];
#pragma unroll
      for (int m = 0; m < 4; ++m){
        int addr = (m*16 + lr)*ROWB + ((ks*64 + lg*16) ^ ((lr & 7) << 4));
        af[m] = *(const bf16x8*)(A + addr);
      }
      __builtin_amdgcn_s_setprio(1);
#pragma unroll
      for (int g = 0; g < 3; ++g)
#pragma unroll
        for (int m = 0; m < 4; ++m)
          acc[g][m] = __builtin_amdgcn_mfma_f32_16x16x32_bf16(af[m], bb[ks%3][g], acc[g][m], 0, 0, 0);
      if (ks == KSTEPS-1){
#pragma unroll
        for (int m = 0; m < 4; ++m)
          accin[m] = __builtin_amdgcn_mfma_f32_16x16x32_bf16(af[m], bnin, accin[m], 0, 0, 0);
      }
      __builtin_amdgcn_s_setprio(0);
    }

    // epilogue: gates + state update; write h (b16) into OTHER parity
#pragma unroll
    for (int m = 0; m < 4; ++m){
#pragma unroll
      for (int rp = 0; rp < 2; ++rp){
        float hold0 = bf2f((short)(hp[m][rp] & 0xffff));
        float hold1 = bf2f((short)(hp[m][rp] >> 16));
        const int r0 = rp*2, r1 = rp*2 + 1;
        float rg0 = sigm(acc[0][m][r0]), rg1 = sigm(acc[0][m][r1]);
        float zg0 = sigm(acc[1][m][r0]), zg1 = sigm(acc[1][m][r1]);
        float n0 = tanh_f(fmaf(rg0, acc[2][m][r0], accin[m][r0]));
        float n1 = tanh_f(fmaf(rg1, acc[2][m][r1], accin[m][r1]));
        float h0 = fmaf(zg0, hold0 - n0, n0);
        float h1 = fmaf(zg1, hold1 - n1, n1);
        unsigned short hb0 = f2bf(h0), hb1 = f2bf(h1);
        hp[m][rp] = (unsigned)hb0 | ((unsigned)hb1 << 16);
        int seq0 = m*16 + lg*4 + r0;
        int seq1 = m*16 + lg*4 + r1;
        *(unsigned short*)(An + seq0*ROWB + (khw ^ ((seq0 & 7) << 4))) = hb0;
        *(unsigned short*)(An + seq1*ROWB + (khw ^ ((seq1 & 7) << 4))) = hb1;
      }
    }
    // stage next step's input section into the other parity
    if (step < PHIST-1){
      int p = step + 1;
      int seq = tid & 63, f = tid >> 6;
      if (f < 8){
        unsigned short v = feat2[((size_t)p*8 + f)*NBC + bc0 + seq];
        *(unsigned short*)(An + seq*ROWB + ((512 + f*2) ^ ((seq & 7) << 4))) = v;
      }
    } else if (step < PHIST + PFUT - 1){
      int s = step - (PHIST-1);
      int seq = tid & 63, d = tid >> 6;
      if (d < 9){
        unsigned v = dfeat[s*9 + d];
        *(unsigned*)(An + seq*ROWB + ((512 + d*4) ^ ((seq & 7) << 4))) = v;
      }
    }
    __syncthreads();   // single barrier per step

    // decoder head: waves 0-3, one 16x16 tile each; reads parity just written
    if (!enc && w < 4){
      int s = step - PHIST;
      f32x4 ah = (f32x4){0.f,0.f,0.f,0.f};
#pragma unroll
      for (int ks = 0; ks < KSTEPS; ++ks){
        int addr = (w*16 + lr)*ROWB + ((ks*64 + lg*16) ^ ((lr & 7) << 4));
        bf16x8 afh = *(const bf16x8*)(An + addr);
        ah = __builtin_amdgcn_mfma_f32_16x16x32_bf16(afh, Bhead[(size_t)ks*64 + l], ah, 0, 0, 0);
      }
      if (lr < 4){
#pragma unroll
        for (int r = 0; r < 4; ++r){
          int seq = w*16 + lg*4 + r;
          int c = c0 + seq;
          float val = ah[r] + last_g[((size_t)b*4 + lr)*CC + c];
          pred[(((size_t)b*PFUT + s)*4 + lr)*CC + c] = val;
        }
      }
    }
  }
}

extern "C" void kernel_launch(void* const* d_in, const int* in_sizes, int n_in,
                              void* d_out, int out_size, void* d_ws, size_t ws_size,
                              hipStream_t stream)
{
  const float* x     = (const float*)d_in[0];
  const float* eWih  = (const float*)d_in[1];
  const float* eWhh  = (const float*)d_in[2];
  const float* ebih  = (const float*)d_in[3];
  const float* ebhh  = (const float*)d_in[4];
  const float* dWih  = (const float*)d_in[5];
  const float* dWhh  = (const float*)d_in[6];
  const float* dbih  = (const float*)d_in[7];
  const float* dbhh  = (const float*)d_in[8];
  const float* femb  = (const float*)d_in[9];
  const float* headW = (const float*)d_in[10];
  const float* headb = (const float*)d_in[11];

  char* ws = (char*)d_ws;
  unsigned short* BencU = (unsigned short*)(ws + OFF_BENC);
  unsigned short* BdecU = (unsigned short*)(ws + OFF_BDEC);
  unsigned short* BheadU= (unsigned short*)(ws + OFF_BHEAD);
  unsigned short* BninU = (unsigned short*)(ws + OFF_BNIN);
  unsigned* dfeat       = (unsigned*)(ws + OFF_DFEAT);
  unsigned short* feat2 = (unsigned short*)(ws + OFF_FEAT);
  float* last_g         = (float*)(ws + OFF_LAST);

  float* xnorm = (float*)d_out;
  float* pred  = (float*)d_out + (size_t)XNELEM;

  prep_kernel<<<227, 256, 0, stream>>>(eWih, eWhh, ebih, ebhh,
      dWih, dWhh, dbih, dbhh, femb, headW, headb,
      BencU, BdecU, BheadU, BninU, dfeat);
  stage_a_kernel<<<256, 128, 0, stream>>>(x, xnorm, feat2, last_g);
  gru_kernel<<<256, 1024, 0, stream>>>(
      (const unsigned char*)BencU, (const unsigned char*)BdecU,
      (const bf16x8*)BheadU, (const bf16x8*)BninU,
      dfeat, feat2, last_g, pred);
}

// Round 10
// 448.440 us; speedup vs baseline: 1.7093x; 1.7093x over previous
//
#include <hip/hip_runtime.h>

// ---------------- problem constants ----------------
#define BB 32
#define TT 720
#define CC 512
#define PHIST 30
#define PFUT 14
#define PLEN 24
#define HID 256
#define NBC (BB*CC)          // 16384 sequences
#define XNELEM (BB*TT*CC)    // 11796480
#define KSTEPS 9             // K aug: 256 h + 32 aug = 288
#define ROWB 640             // LDS bytes per seq row (576 + pad for XOR swizzle)

// gate pre-scales folded into weights (prep):
//   r,z gates:  * -log2(e)  -> sigmoid(x) = rcp(1 + exp2(acc))
//   n gate:     * 2*log2(e) -> tanh(y)    = 1 - 2*rcp(1 + exp2(arg))
#define SIGM_SCALE (-1.44269504f)
#define TANH_SCALE ( 2.88539008f)

// ws layout (bytes)
#define OFF_BENC   0u           // ks-major: 9 ks * 48 tiles * 64 lanes * 16 B = 442368
#define OFF_BDEC   442368u
#define OFF_BHEAD  884736u      // 9*64*16 = 9216
#define OFF_BNIN   893952u      // 2 * 16 tiles * 64 lanes * 16 B = 32768 (enc, dec)
#define OFF_DFEAT  926720u      // 14*9*4 = 504 (padded 512)
#define OFF_FEAT   927232u      // 30*8*16384*2 = 7864320
#define OFF_LAST   8791552u     // 32*4*512*4 = 262144

typedef short bf16x8 __attribute__((ext_vector_type(8)));
typedef float f32x4 __attribute__((ext_vector_type(4)));

__device__ __forceinline__ unsigned short f2bf(float f){
  unsigned u = __float_as_uint(f);
  u = (u + 0x7fffu + ((u >> 16) & 1u)) >> 16;
  return (unsigned short)u;
}

// h-column K-permutation: k = wv*32 + lr*2 + jt  <->  n = wv*32 + jt*16 + lr
__device__ __forceinline__ int nh_of_k(int k){
  return (k & 0xE0) | ((k & 1) << 4) | ((k >> 1) & 15);
}

// ---------------- prep: pack weights into MFMA B-fragment order ----------------
// Benc/Bdec ks-major: [ks][tile(=wv*6+t6)][lane][8 bf16], gate scales prefolded.
__global__ void prep_kernel(
    const float* __restrict__ eWih, const float* __restrict__ eWhh,
    const float* __restrict__ ebih, const float* __restrict__ ebhh,
    const float* __restrict__ dWih, const float* __restrict__ dWhh,
    const float* __restrict__ dbih, const float* __restrict__ dbhh,
    const float* __restrict__ femb, const float* __restrict__ headW,
    const float* __restrict__ headb,
    unsigned short* __restrict__ Benc, unsigned short* __restrict__ Bdec,
    unsigned short* __restrict__ Bhead, unsigned short* __restrict__ Bnin,
    unsigned* __restrict__ dfeat)
{
  const int NE = 48*9*64; // 27648
  int id = blockIdx.x*256 + threadIdx.x;
  if (id < 2*NE){
    bool isenc = id < NE;
    int s = isenc ? id : id - NE;
    int g = s / 576, rem = s % 576, ks = rem / 64, lane = rem % 64;
    int wv = g / 6, t6 = g % 6;
    int n = (t6 >> 1)*256 + wv*32 + (t6 & 1)*16 + (lane & 15);
    int kb = ks*32 + (lane >> 4)*8;
    unsigned short* outp = (isenc ? Benc : Bdec) + ((size_t)((ks*48 + g)*64 + lane))*8;
    const float* Whh = isenc ? eWhh : dWhh;
    const float* Wih = isenc ? eWih : dWih;
    const float* bih = isenc ? ebih : dbih;
    const float* bhh = isenc ? ebhh : dbhh;
    const int FN = isenc ? 7 : 16;
    const int KC = 256 + FN;
    const float sc = (n < 512) ? SIGM_SCALE : TANH_SCALE;
    for (int e = 0; e < 8; ++e){
      int k = kb + e;
      float v;
      if (k < 256)            v = Whh[n*256 + nh_of_k(k)];
      else if (n < 512){      // r,z gates: input part + fused bias column
        if (k < KC)           v = Wih[n*FN + (k - 256)];
        else if (k == KC)     v = bih[n] + bhh[n];
        else                  v = 0.f;
      } else {                // n gate: only hidden bias (input part in Bnin)
        v = (k == KC) ? bhh[n] : 0.f;
      }
      outp[e] = f2bf(v*sc);
    }
  } else if (id < 2*NE + 576){
    int s = id - 2*NE;
    int ks = s / 64, lane = s % 64;
    int o = lane & 15, kb = ks*32 + (lane >> 4)*8;
    unsigned short* outp = Bhead + (size_t)s*8;
    for (int e = 0; e < 8; ++e){
      int k = kb + e;
      float v = 0.f;
      if (o < 4){
        if (k < 256)       v = headW[o*256 + nh_of_k(k)];
        else if (k == 272) v = headb[o];
      }
      outp[e] = f2bf(v);
    }
  } else if (id < 2*NE + 576 + 2048){
    // Bnin: i_n input-part tiles (n gate -> TANH_SCALE prefolded)
    int s3 = id - (2*NE + 576);
    int ed = s3 >> 10, rem = s3 & 1023;
    int wv = rem >> 7, jt = (rem >> 6) & 1, lane = rem & 63;
    int n = 512 + wv*32 + jt*16 + (lane & 15);
    unsigned short* outp = Bnin + (size_t)ed*8192 + (size_t)(((wv*2 + jt)*64) + lane)*8;
    const int FN = ed ? 16 : 7;
    const float* Wih = ed ? dWih : eWih;
    const float* bih = ed ? dbih : ebih;
    for (int e = 0; e < 8; ++e){
      int kk = (lane >> 4)*8 + e;
      float v;
      if (kk < FN)       v = Wih[n*FN + kk];
      else if (kk == FN) v = bih[n];
      else               v = 0.f;
      outp[e] = f2bf(v*TANH_SCALE);
    }
  } else if (id < 2*NE + 576 + 2048 + PFUT*9){
    int s2 = id - (2*NE + 576 + 2048);
    int st = s2 / 9, d = s2 % 9;
    unsigned v;
    if (d < 8) v = (unsigned)f2bf(femb[st*16 + 2*d]) | ((unsigned)f2bf(femb[st*16 + 2*d + 1]) << 16);
    else       v = (unsigned)f2bf(1.0f);
    dfeat[s2] = v;
  }
}

// ---------------- stage A: SWT + stats + features + x_norm ----------------
__global__ __launch_bounds__(128,4) void stage_a_kernel(
    const float* __restrict__ x, float* __restrict__ xnorm,
    unsigned short* __restrict__ feat2, float* __restrict__ last_g)
{
  __shared__ float sG[2][2][64];
  const int tid = threadIdx.x, lane = tid & 63, half = tid >> 6;
  const int bc = blockIdx.x*64 + lane;
  const int b = bc >> 9, c = bc & 511;
  const float* xp = x + (size_t)b*TT*CC + c;
  float* op = xnorm + (size_t)b*TT*CC + c;
  float gsum = 0.f, gss = 0.f;
  float lastv[4] = {0,0,0,0};
  const float inv24 = 1.f/24.f, inv23 = 1.f/23.f;
  const int p0 = half*15, p1 = p0 + 15;

  for (int p = p0; p < p1; ++p){
    const int t0 = p*PLEN;
    float xl[31];
#pragma unroll
    for (int i = 0; i < 31; ++i){
      int t = t0 - 4 + i;
      t = (t < 0) ? -t : ((t >= TT) ? (2*TT - 2 - t) : t);
      xl[i] = xp[(size_t)t*CC];
    }
    float a1l[30];
#pragma unroll
    for (int j = 0; j < 30; ++j) a1l[j] = 0.5f*(xl[j] + xl[j+1]);
    if (p == 0){ a1l[2] = a1l[4]; a1l[1] = a1l[5]; a1l[0] = a1l[6]; }
    if (p == PHIST-1){ a1l[27] = a1l[25]; a1l[28] = a1l[24]; a1l[29] = a1l[23]; }
    float a2l[28];
#pragma unroll
    for (int m = 0; m < 28; ++m) a2l[m] = 0.5f*(a1l[m] + a1l[m+2]);
    if (p == 0){ a2l[1] = a2l[3]; a2l[0] = a2l[4]; }
    if (p == PHIST-1){ a2l[26] = a2l[24]; a2l[27] = a2l[23]; }
    float a3l[24], d1l[24], d2l[24], d3l[24];
    float sL=0, sL2=0, s2=0, s22=0, s3=0, s32=0, sH2=0;
#pragma unroll
    for (int n = 0; n < 24; ++n){
      float a3 = 0.5f*(a2l[n] + a2l[n+4]);
      float d1 = xl[n+4] - a1l[n+3];
      float d2 = a1l[n+3] - a2l[n+2];
      float d3 = a2l[n+2] - a3;
      a3l[n]=a3; d1l[n]=d1; d2l[n]=d2; d3l[n]=d3;
      sL += a3; sL2 += a3*a3;
      s2 += d2; s22 += d2*d2;
      s3 += d3; s32 += d3*d3;
      sH2 += d1*d1;
      gsum += a3; gss += a3*a3;
    }
    float mu   = sL*inv24;
    float sigL = fmaxf(sqrtf(fmaxf((sL2 - sL*sL*inv24)*inv23, 0.f)), 1e-3f);
    float sig2 = fmaxf(sqrtf(fmaxf((s22 - s2*s2*inv24)*inv23, 0.f)), 1e-3f);
    float sig3 = fmaxf(sqrtf(fmaxf((s32 - s3*s3*inv24)*inv23, 0.f)), 1e-3f);
    float EL = sL2*inv24, E2 = s22*inv24, E3 = s32*inv24, EH = sH2*inv24;
    float rho = EH / (EL + EH + E2 + E3 + 1e-6f);
    float lsl = __logf(sigL), ls2 = __logf(sig2), ls3 = __logf(sig3);
    size_t fb = ((size_t)p*8)*NBC + bc;
    feat2[fb + 0*NBC] = f2bf(mu);
    feat2[fb + 1*NBC] = f2bf(lsl);
    feat2[fb + 2*NBC] = f2bf(ls2);
    feat2[fb + 3*NBC] = f2bf(ls3);
    feat2[fb + 4*NBC] = f2bf(rho);
    if (p == PHIST-1){ lastv[0]=mu; lastv[1]=lsl; lastv[2]=ls2; lastv[3]=ls3; }
    float iL = 1.f/sigL, i2 = 1.f/sig2, i3 = 1.f/sig3;
#pragma unroll
    for (int n = 0; n < 24; ++n){
      float v = (a3l[n]-mu)*iL + d1l[n] + d2l[n]*i2 + d3l[n]*i3;
      op[(size_t)(t0+n)*CC] = v;
    }
  }
  sG[half][0][lane] = gsum; sG[half][1][lane] = gss;
  __syncthreads();
  float gs = sG[0][0][lane] + sG[1][0][lane];
  float g2 = sG[0][1][lane] + sG[1][1][lane];
  float mug  = gs*(1.f/720.f);
  float sigg = fmaxf(sqrtf(fmaxf((g2 - gs*gs*(1.f/720.f))*(1.f/719.f), 0.f)), 1e-3f);
  unsigned short f5 = f2bf(mug), f6 = f2bf(__logf(sigg)), f7 = f2bf(1.0f);
  for (int p = p0; p < p1; ++p){
    size_t fb = ((size_t)p*8)*NBC + bc;
    feat2[fb + 5*NBC] = f5;
    feat2[fb + 6*NBC] = f6;
    feat2[fb + 7*NBC] = f7;
  }
  if (half == 1){
#pragma unroll
    for (int o = 0; o < 4; ++o) last_g[((size_t)b*4 + o)*CC + c] = lastv[o];
  }
}

// ---------------- GRU: encoder 30 + decoder 14 + fused head ----------------
// R8 structure (256 blocks x 512 thr, 3-slot half-kstep ring, Ab[2] 1-barrier)
// + VALU cuts: zero-init via zf C-operand, prefolded gate scales,
// v_cvt_pk_bf16_f32 h-pack, 1-op h-unpacks.
__global__ __launch_bounds__(512,2) void gru_kernel(
    const unsigned char* __restrict__ BencB, const unsigned char* __restrict__ BdecB,
    const bf16x8* __restrict__ Bhead, const bf16x8* __restrict__ BninP,
    const unsigned* __restrict__ dfeat,       // [14][9] packed dec A-aug dwords
    const unsigned short* __restrict__ feat2, // [30][8][16384] bf16
    const float* __restrict__ last_g,         // [32][4][512]
    float* __restrict__ pred)                 // [32][14][4][512]
{
  __shared__ unsigned char Ab[2][64*ROWB];    // 2 x 40960
  const int tid = threadIdx.x;
  const int w = tid >> 6, l = tid & 63, lr = l & 15, lg = l >> 4;
  const int bc0 = blockIdx.x * 64;
  const int b = bc0 >> 9, c0 = bc0 & 511;

  for (int i = tid; i < 2*64*ROWB/4; i += 512) ((unsigned*)Ab)[i] = 0u;

  // per-wave B base pointers (ks-major; wave's 6 tiles contiguous per ks)
  const unsigned char* Bwe = BencB + (size_t)(w*6*64 + l)*16;
  const unsigned char* Bwd = BdecB + (size_t)(w*6*64 + l)*16;

  // i_n input-part tiles (resident; swapped at decoder start)
  bf16x8 bnin0 = BninP[(size_t)(w*2 + 0)*64 + l];
  bf16x8 bnin1 = BninP[(size_t)(w*2 + 1)*64 + l];

  // packed h state: bf16 pair (jt0 | jt1<<16) per (m, r)
  unsigned hp[4][4];
#pragma unroll
  for (int m=0;m<4;m++)
#pragma unroll
    for (int r=0;r<4;r++) hp[m][r] = 0u;

  const f32x4 zf = {0.f, 0.f, 0.f, 0.f};   // loop-invariant zero C-operand

  // B ring: 3 slots x 3 tiles; preload groups 0,1 of step 0 (ks0 halves 0,1)
  bf16x8 bb[3][3];
#pragma unroll
  for (int q=0;q<3;q++){
    bb[0][q] = *(const bf16x8*)(Bwe + q*1024);
    bb[1][q] = *(const bf16x8*)(Bwe + 3072 + q*1024);
  }

  __syncthreads();
  { // stage encoder features for step 0 into parity 0
    int seq = tid & 63, f = tid >> 6;
    unsigned short v = feat2[((size_t)0*8 + f)*NBC + bc0 + seq];
    *(unsigned short*)(Ab[0] + seq*ROWB + ((512 + f*2) ^ ((seq & 7) << 4))) = v;
  }
  __syncthreads();

  for (int step = 0; step < PHIST + PFUT; ++step){
    const bool enc = step < PHIST;
    const int sp = step & 1;
    const unsigned char* A  = Ab[sp];
    unsigned char*       An = Ab[sp^1];
    const unsigned char* Bc = enc ? Bwe : Bwd;
    const unsigned char* Bn = (step == PHIST-1) ? Bwd :
                              ((step >= PHIST+PFUT-1) ? Bwe : Bc);
    if (step == PHIST){
      bnin0 = BninP[1024 + (size_t)(w*2 + 0)*64 + l];
      bnin1 = BninP[1024 + (size_t)(w*2 + 1)*64 + l];
    }

    f32x4 acc[6][4];
    f32x4 accin[2][4];

    bf16x8 af[4];
#pragma unroll
    for (int g = 0; g < 18; ++g){
      const int ks = g >> 1, tb = (g & 1)*3;
      // prefetch group g+2 into slot (g+2)%3 (wraps into next step's groups)
      {
        const int tg = g + 2;
        const unsigned char* bp = (tg < 18) ? Bc : Bn;
        const int rg = (tg < 18) ? tg : (tg - 18);
        const size_t off = (size_t)(rg >> 1)*49152 + (rg & 1)*3072;
#pragma unroll
        for (int q = 0; q < 3; ++q)
          bb[tg % 3][q] = *(const bf16x8*)(bp + off + q*1024);
      }
      if ((g & 1) == 0){
#pragma unroll
        for (int m = 0; m < 4; ++m){
          int addr = (m*16 + lr)*ROWB + ((ks*64 + lg*16) ^ ((lr & 7) << 4));
          af[m] = *(const bf16x8*)(A + addr);
        }
      }
      if (g < 2){       // ks==0: C = zf (no acc zero-init pass needed)
#pragma unroll
        for (int q = 0; q < 3; ++q)
#pragma unroll
          for (int m = 0; m < 4; ++m)
            acc[tb+q][m] = __builtin_amdgcn_mfma_f32_16x16x32_bf16(af[m], bb[g%3][q], zf, 0, 0, 0);
      } else {
#pragma unroll
        for (int q = 0; q < 3; ++q)
#pragma unroll
          for (int m = 0; m < 4; ++m)
            acc[tb+q][m] = __builtin_amdgcn_mfma_f32_16x16x32_bf16(af[m], bb[g%3][q], acc[tb+q][m], 0, 0, 0);
      }
      if (g == 17){
        // af holds ks=8 (aug) fragments (loaded at g==16); C = zf
#pragma unroll
        for (int m = 0; m < 4; ++m){
          accin[0][m] = __builtin_amdgcn_mfma_f32_16x16x32_bf16(af[m], bnin0, zf, 0, 0, 0);
          accin[1][m] = __builtin_amdgcn_mfma_f32_16x16x32_bf16(af[m], bnin1, zf, 0, 0, 0);
        }
      }
    }

    // epilogue: gates (scales prefolded) + state update
#pragma unroll
    for (int m = 0; m < 4; ++m){
#pragma unroll
      for (int r = 0; r < 4; ++r){
        float h0 = __uint_as_float(hp[m][r] << 16);
        float h1 = __uint_as_float(hp[m][r] & 0xffff0000u);
        float rg0 = __builtin_amdgcn_rcpf(1.f + __builtin_amdgcn_exp2f(acc[0][m][r]));
        float rg1 = __builtin_amdgcn_rcpf(1.f + __builtin_amdgcn_exp2f(acc[1][m][r]));
        float zg0 = __builtin_amdgcn_rcpf(1.f + __builtin_amdgcn_exp2f(acc[2][m][r]));
        float zg1 = __builtin_amdgcn_rcpf(1.f + __builtin_amdgcn_exp2f(acc[3][m][r]));
        float n0 = fmaf(-2.f, __builtin_amdgcn_rcpf(1.f + __builtin_amdgcn_exp2f(
                       fmaf(rg0, acc[4][m][r], accin[0][m][r]))), 1.f);
        float n1 = fmaf(-2.f, __builtin_amdgcn_rcpf(1.f + __builtin_amdgcn_exp2f(
                       fmaf(rg1, acc[5][m][r], accin[1][m][r]))), 1.f);
        h0 = fmaf(zg0, h0 - n0, n0);
        h1 = fmaf(zg1, h1 - n1, n1);
        unsigned pk;
        asm("v_cvt_pk_bf16_f32 %0, %1, %2" : "=v"(pk) : "v"(h0), "v"(h1));
        hp[m][r] = pk;
      }
    }

    // write packed h into OTHER parity + stage next step's input section there
#pragma unroll
    for (int m = 0; m < 4; ++m)
#pragma unroll
      for (int r = 0; r < 4; ++r){
        int seq = m*16 + lg*4 + r;
        *(unsigned*)(An + seq*ROWB + ((w*64 + lr*4) ^ ((seq & 7) << 4))) = hp[m][r];
      }
    if (step < PHIST-1){
      int p = step + 1;
      int seq = tid & 63, f = tid >> 6;
      unsigned short v = feat2[((size_t)p*8 + f)*NBC + bc0 + seq];
      *(unsigned short*)(An + seq*ROWB + ((512 + f*2) ^ ((seq & 7) << 4))) = v;
    } else if (step < PHIST + PFUT - 1){
      int s = step - (PHIST-1);
      int seq = tid & 63;
      for (int d = tid >> 6; d < 9; d += 8){
        unsigned v = dfeat[s*9 + d];
        *(unsigned*)(An + seq*ROWB + ((512 + d*4) ^ ((seq & 7) << 4))) = v;
      }
    }
    __syncthreads();   // single barrier per step

    // decoder head (unscaled Bhead); reads the parity just written
    if (!enc && w < 4){
      int s = step - PHIST;
      f32x4 ah = (f32x4){0.f,0.f,0.f,0.f};
#pragma unroll
      for (int ks = 0; ks < KSTEPS; ++ks){
        int addr = (w*16 + lr)*ROWB + ((ks*64 + lg*16) ^ ((lr & 7) << 4));
        bf16x8 afh = *(const bf16x8*)(An + addr);
        ah = __builtin_amdgcn_mfma_f32_16x16x32_bf16(afh, Bhead[(size_t)ks*64 + l], ah, 0, 0, 0);
      }
      if (lr < 4){
#pragma unroll
        for (int r = 0; r < 4; ++r){
          int seq = w*16 + lg*4 + r;
          int c = c0 + seq;
          float val = ah[r] + last_g[((size_t)b*4 + lr)*CC + c];
          pred[(((size_t)b*PFUT + s)*4 + lr)*CC + c] = val;
        }
      }
    }
  }
}

extern "C" void kernel_launch(void* const* d_in, const int* in_sizes, int n_in,
                              void* d_out, int out_size, void* d_ws, size_t ws_size,
                              hipStream_t stream)
{
  const float* x     = (const float*)d_in[0];
  const float* eWih  = (const float*)d_in[1];
  const float* eWhh  = (const float*)d_in[2];
  const float* ebih  = (const float*)d_in[3];
  const float* ebhh  = (const float*)d_in[4];
  const float* dWih  = (const float*)d_in[5];
  const float* dWhh  = (const float*)d_in[6];
  const float* dbih  = (const float*)d_in[7];
  const float* dbhh  = (const float*)d_in[8];
  const float* femb  = (const float*)d_in[9];
  const float* headW = (const float*)d_in[10];
  const float* headb = (const float*)d_in[11];

  char* ws = (char*)d_ws;
  unsigned short* BencU = (unsigned short*)(ws + OFF_BENC);
  unsigned short* BdecU = (unsigned short*)(ws + OFF_BDEC);
  unsigned short* BheadU= (unsigned short*)(ws + OFF_BHEAD);
  unsigned short* BninU = (unsigned short*)(ws + OFF_BNIN);
  unsigned* dfeat       = (unsigned*)(ws + OFF_DFEAT);
  unsigned short* feat2 = (unsigned short*)(ws + OFF_FEAT);
  float* last_g         = (float*)(ws + OFF_LAST);

  float* xnorm = (float*)d_out;
  float* pred  = (float*)d_out + (size_t)XNELEM;

  prep_kernel<<<227, 256, 0, stream>>>(eWih, eWhh, ebih, ebhh,
      dWih, dWhh, dbih, dbhh, femb, headW, headb,
      BencU, BdecU, BheadU, BninU, dfeat);
  stage_a_kernel<<<256, 128, 0, stream>>>(x, xnorm, feat2, last_g);
  gru_kernel<<<256, 512, 0, stream>>>(
      (const unsigned char*)BencU, (const unsigned char*)BdecU,
      (const bf16x8*)BheadU, (const bf16x8*)BninU,
      dfeat, feat2, last_g, pred);
}

// Round 11
// 404.195 us; speedup vs baseline: 1.8964x; 1.1095x over previous
//
#include <hip/hip_runtime.h>

// ---------------- problem constants ----------------
#define BB 32
#define TT 720
#define CC 512
#define PHIST 30
#define PFUT 14
#define PLEN 24
#define HID 256
#define NBC (BB*CC)          // 16384 sequences
#define XNELEM (BB*TT*CC)    // 11796480
#define KSTEPS 9             // K aug: 256 h + 32 aug = 288
#define ROWB 640             // LDS bytes per seq row (576 + pad for XOR swizzle)

// gate pre-scales folded into weights (prep):
//   r,z gates:  * -log2(e)  -> sigmoid(x) = rcp(1 + exp2(acc))
//   n gate:     * 2*log2(e) -> tanh(y)    = 1 - 2*rcp(1 + exp2(arg))
#define SIGM_SCALE (-1.44269504f)
#define TANH_SCALE ( 2.88539008f)

// ws layout (bytes)
#define OFF_BENC   0u           // ks-major: 9 ks * 48 tiles * 64 lanes * 16 B = 442368
#define OFF_BDEC   442368u
#define OFF_BHEAD  884736u      // 9*64*16 = 9216
#define OFF_BNIN   893952u      // 2 * 16 tiles * 64 lanes * 16 B = 32768 (enc, dec)
#define OFF_DFEAT  926720u      // 14*9*4 = 504 (padded 512)
#define OFF_FEAT   927232u      // 30*8*16384*2 = 7864320
#define OFF_LAST   8791552u     // 32*4*512*4 = 262144

typedef short bf16x8 __attribute__((ext_vector_type(8)));
typedef float f32x4 __attribute__((ext_vector_type(4)));

__device__ __forceinline__ unsigned short f2bf(float f){
  unsigned u = __float_as_uint(f);
  u = (u + 0x7fffu + ((u >> 16) & 1u)) >> 16;
  return (unsigned short)u;
}

// h-column K-permutation: k = wv*32 + lr*2 + jt  <->  n = wv*32 + jt*16 + lr
__device__ __forceinline__ int nh_of_k(int k){
  return (k & 0xE0) | ((k & 1) << 4) | ((k >> 1) & 15);
}

// ---------------- prep: pack weights into MFMA B-fragment order ----------------
// Benc/Bdec ks-major: [ks][tile(=wv*6+t6)][lane][8 bf16], gate scales prefolded.
__global__ void prep_kernel(
    const float* __restrict__ eWih, const float* __restrict__ eWhh,
    const float* __restrict__ ebih, const float* __restrict__ ebhh,
    const float* __restrict__ dWih, const float* __restrict__ dWhh,
    const float* __restrict__ dbih, const float* __restrict__ dbhh,
    const float* __restrict__ femb, const float* __restrict__ headW,
    const float* __restrict__ headb,
    unsigned short* __restrict__ Benc, unsigned short* __restrict__ Bdec,
    unsigned short* __restrict__ Bhead, unsigned short* __restrict__ Bnin,
    unsigned* __restrict__ dfeat)
{
  const int NE = 48*9*64; // 27648
  int id = blockIdx.x*256 + threadIdx.x;
  if (id < 2*NE){
    bool isenc = id < NE;
    int s = isenc ? id : id - NE;
    int g = s / 576, rem = s % 576, ks = rem / 64, lane = rem % 64;
    int wv = g / 6, t6 = g % 6;
    int n = (t6 >> 1)*256 + wv*32 + (t6 & 1)*16 + (lane & 15);
    int kb = ks*32 + (lane >> 4)*8;
    unsigned short* outp = (isenc ? Benc : Bdec) + ((size_t)((ks*48 + g)*64 + lane))*8;
    const float* Whh = isenc ? eWhh : dWhh;
    const float* Wih = isenc ? eWih : dWih;
    const float* bih = isenc ? ebih : dbih;
    const float* bhh = isenc ? ebhh : dbhh;
    const int FN = isenc ? 7 : 16;
    const int KC = 256 + FN;
    const float sc = (n < 512) ? SIGM_SCALE : TANH_SCALE;
    for (int e = 0; e < 8; ++e){
      int k = kb + e;
      float v;
      if (k < 256)            v = Whh[n*256 + nh_of_k(k)];
      else if (n < 512){      // r,z gates: input part + fused bias column
        if (k < KC)           v = Wih[n*FN + (k - 256)];
        else if (k == KC)     v = bih[n] + bhh[n];
        else                  v = 0.f;
      } else {                // n gate: only hidden bias (input part in Bnin)
        v = (k == KC) ? bhh[n] : 0.f;
      }
      outp[e] = f2bf(v*sc);
    }
  } else if (id < 2*NE + 576){
    int s = id - 2*NE;
    int ks = s / 64, lane = s % 64;
    int o = lane & 15, kb = ks*32 + (lane >> 4)*8;
    unsigned short* outp = Bhead + (size_t)s*8;
    for (int e = 0; e < 8; ++e){
      int k = kb + e;
      float v = 0.f;
      if (o < 4){
        if (k < 256)       v = headW[o*256 + nh_of_k(k)];
        else if (k == 272) v = headb[o];
      }
      outp[e] = f2bf(v);
    }
  } else if (id < 2*NE + 576 + 2048){
    // Bnin: i_n input-part tiles (n gate -> TANH_SCALE prefolded)
    int s3 = id - (2*NE + 576);
    int ed = s3 >> 10, rem = s3 & 1023;
    int wv = rem >> 7, jt = (rem >> 6) & 1, lane = rem & 63;
    int n = 512 + wv*32 + jt*16 + (lane & 15);
    unsigned short* outp = Bnin + (size_t)ed*8192 + (size_t)(((wv*2 + jt)*64) + lane)*8;
    const int FN = ed ? 16 : 7;
    const float* Wih = ed ? dWih : eWih;
    const float* bih = ed ? dbih : ebih;
    for (int e = 0; e < 8; ++e){
      int kk = (lane >> 4)*8 + e;
      float v;
      if (kk < FN)       v = Wih[n*FN + kk];
      else if (kk == FN) v = bih[n];
      else               v = 0.f;
      outp[e] = f2bf(v*TANH_SCALE);
    }
  } else if (id < 2*NE + 576 + 2048 + PFUT*9){
    int s2 = id - (2*NE + 576 + 2048);
    int st = s2 / 9, d = s2 % 9;
    unsigned v;
    if (d < 8) v = (unsigned)f2bf(femb[st*16 + 2*d]) | ((unsigned)f2bf(femb[st*16 + 2*d + 1]) << 16);
    else       v = (unsigned)f2bf(1.0f);
    dfeat[s2] = v;
  }
}

// ---------------- stage A: SWT + stats + features + x_norm ----------------
__global__ __launch_bounds__(128,4) void stage_a_kernel(
    const float* __restrict__ x, float* __restrict__ xnorm,
    unsigned short* __restrict__ feat2, float* __restrict__ last_g)
{
  __shared__ float sG[2][2][64];
  const int tid = threadIdx.x, lane = tid & 63, half = tid >> 6;
  const int bc = blockIdx.x*64 + lane;
  const int b = bc >> 9, c = bc & 511;
  const float* xp = x + (size_t)b*TT*CC + c;
  float* op = xnorm + (size_t)b*TT*CC + c;
  float gsum = 0.f, gss = 0.f;
  float lastv[4] = {0,0,0,0};
  const float inv24 = 1.f/24.f, inv23 = 1.f/23.f;
  const int p0 = half*15, p1 = p0 + 15;

  for (int p = p0; p < p1; ++p){
    const int t0 = p*PLEN;
    float xl[31];
#pragma unroll
    for (int i = 0; i < 31; ++i){
      int t = t0 - 4 + i;
      t = (t < 0) ? -t : ((t >= TT) ? (2*TT - 2 - t) : t);
      xl[i] = xp[(size_t)t*CC];
    }
    float a1l[30];
#pragma unroll
    for (int j = 0; j < 30; ++j) a1l[j] = 0.5f*(xl[j] + xl[j+1]);
    if (p == 0){ a1l[2] = a1l[4]; a1l[1] = a1l[5]; a1l[0] = a1l[6]; }
    if (p == PHIST-1){ a1l[27] = a1l[25]; a1l[28] = a1l[24]; a1l[29] = a1l[23]; }
    float a2l[28];
#pragma unroll
    for (int m = 0; m < 28; ++m) a2l[m] = 0.5f*(a1l[m] + a1l[m+2]);
    if (p == 0){ a2l[1] = a2l[3]; a2l[0] = a2l[4]; }
    if (p == PHIST-1){ a2l[26] = a2l[24]; a2l[27] = a2l[23]; }
    float a3l[24], d1l[24], d2l[24], d3l[24];
    float sL=0, sL2=0, s2=0, s22=0, s3=0, s32=0, sH2=0;
#pragma unroll
    for (int n = 0; n < 24; ++n){
      float a3 = 0.5f*(a2l[n] + a2l[n+4]);
      float d1 = xl[n+4] - a1l[n+3];
      float d2 = a1l[n+3] - a2l[n+2];
      float d3 = a2l[n+2] - a3;
      a3l[n]=a3; d1l[n]=d1; d2l[n]=d2; d3l[n]=d3;
      sL += a3; sL2 += a3*a3;
      s2 += d2; s22 += d2*d2;
      s3 += d3; s32 += d3*d3;
      sH2 += d1*d1;
      gsum += a3; gss += a3*a3;
    }
    float mu   = sL*inv24;
    float sigL = fmaxf(sqrtf(fmaxf((sL2 - sL*sL*inv24)*inv23, 0.f)), 1e-3f);
    float sig2 = fmaxf(sqrtf(fmaxf((s22 - s2*s2*inv24)*inv23, 0.f)), 1e-3f);
    float sig3 = fmaxf(sqrtf(fmaxf((s32 - s3*s3*inv24)*inv23, 0.f)), 1e-3f);
    float EL = sL2*inv24, E2 = s22*inv24, E3 = s32*inv24, EH = sH2*inv24;
    float rho = EH / (EL + EH + E2 + E3 + 1e-6f);
    float lsl = __logf(sigL), ls2 = __logf(sig2), ls3 = __logf(sig3);
    size_t fb = ((size_t)p*8)*NBC + bc;
    feat2[fb + 0*NBC] = f2bf(mu);
    feat2[fb + 1*NBC] = f2bf(lsl);
    feat2[fb + 2*NBC] = f2bf(ls2);
    feat2[fb + 3*NBC] = f2bf(ls3);
    feat2[fb + 4*NBC] = f2bf(rho);
    if (p == PHIST-1){ lastv[0]=mu; lastv[1]=lsl; lastv[2]=ls2; lastv[3]=ls3; }
    float iL = 1.f/sigL, i2 = 1.f/sig2, i3 = 1.f/sig3;
#pragma unroll
    for (int n = 0; n < 24; ++n){
      float v = (a3l[n]-mu)*iL + d1l[n] + d2l[n]*i2 + d3l[n]*i3;
      op[(size_t)(t0+n)*CC] = v;
    }
  }
  sG[half][0][lane] = gsum; sG[half][1][lane] = gss;
  __syncthreads();
  float gs = sG[0][0][lane] + sG[1][0][lane];
  float g2 = sG[0][1][lane] + sG[1][1][lane];
  float mug  = gs*(1.f/720.f);
  float sigg = fmaxf(sqrtf(fmaxf((g2 - gs*gs*(1.f/720.f))*(1.f/719.f), 0.f)), 1e-3f);
  unsigned short f5 = f2bf(mug), f6 = f2bf(__logf(sigg)), f7 = f2bf(1.0f);
  for (int p = p0; p < p1; ++p){
    size_t fb = ((size_t)p*8)*NBC + bc;
    feat2[fb + 5*NBC] = f5;
    feat2[fb + 6*NBC] = f6;
    feat2[fb + 7*NBC] = f7;
  }
  if (half == 1){
#pragma unroll
    for (int o = 0; o < 4; ++o) last_g[((size_t)b*4 + o)*CC + c] = lastv[o];
  }
}

// ---------------- GRU: encoder 30 + decoder 14 + fused head ----------------
// R10 structure + T14 split: next-step feature loads issued BEFORE the
// epilogue (HBM latency hides under the transcendental burst), LDS writes
// after; h ds_writes merged into the gate loop.
__global__ __launch_bounds__(512,2) void gru_kernel(
    const unsigned char* __restrict__ BencB, const unsigned char* __restrict__ BdecB,
    const bf16x8* __restrict__ Bhead, const bf16x8* __restrict__ BninP,
    const unsigned* __restrict__ dfeat,       // [14][9] packed dec A-aug dwords
    const unsigned short* __restrict__ feat2, // [30][8][16384] bf16
    const float* __restrict__ last_g,         // [32][4][512]
    float* __restrict__ pred)                 // [32][14][4][512]
{
  __shared__ unsigned char Ab[2][64*ROWB];    // 2 x 40960
  const int tid = threadIdx.x;
  const int w = tid >> 6, l = tid & 63, lr = l & 15, lg = l >> 4;
  const int bc0 = blockIdx.x * 64;
  const int b = bc0 >> 9, c0 = bc0 & 511;

  for (int i = tid; i < 2*64*ROWB/4; i += 512) ((unsigned*)Ab)[i] = 0u;

  // per-wave B base pointers (ks-major; wave's 6 tiles contiguous per ks)
  const unsigned char* Bwe = BencB + (size_t)(w*6*64 + l)*16;
  const unsigned char* Bwd = BdecB + (size_t)(w*6*64 + l)*16;

  // i_n input-part tiles (resident; swapped at decoder start)
  bf16x8 bnin0 = BninP[(size_t)(w*2 + 0)*64 + l];
  bf16x8 bnin1 = BninP[(size_t)(w*2 + 1)*64 + l];

  // packed h state: bf16 pair (jt0 | jt1<<16) per (m, r)
  unsigned hp[4][4];
#pragma unroll
  for (int m=0;m<4;m++)
#pragma unroll
    for (int r=0;r<4;r++) hp[m][r] = 0u;

  const f32x4 zf = {0.f, 0.f, 0.f, 0.f};   // loop-invariant zero C-operand

  // B ring: 3 slots x 3 tiles; preload groups 0,1 of step 0 (ks0 halves 0,1)
  bf16x8 bb[3][3];
#pragma unroll
  for (int q=0;q<3;q++){
    bb[0][q] = *(const bf16x8*)(Bwe + q*1024);
    bb[1][q] = *(const bf16x8*)(Bwe + 3072 + q*1024);
  }

  const int seqx = tid & 63, fx = tid >> 6;

  __syncthreads();
  { // stage encoder features for step 0 into parity 0
    unsigned short v = feat2[((size_t)0*8 + fx)*NBC + bc0 + seqx];
    *(unsigned short*)(Ab[0] + seqx*ROWB + ((512 + fx*2) ^ ((seqx & 7) << 4))) = v;
  }
  __syncthreads();

  for (int step = 0; step < PHIST + PFUT; ++step){
    const bool enc = step < PHIST;
    const int sp = step & 1;
    const unsigned char* A  = Ab[sp];
    unsigned char*       An = Ab[sp^1];
    const unsigned char* Bc = enc ? Bwe : Bwd;
    const unsigned char* Bn = (step == PHIST-1) ? Bwd :
                              ((step >= PHIST+PFUT-1) ? Bwe : Bc);
    if (step == PHIST){
      bnin0 = BninP[1024 + (size_t)(w*2 + 0)*64 + l];
      bnin1 = BninP[1024 + (size_t)(w*2 + 1)*64 + l];
    }

    f32x4 acc[6][4];
    f32x4 accin[2][4];

    bf16x8 af[4];
#pragma unroll
    for (int g = 0; g < 18; ++g){
      const int ks = g >> 1, tb = (g & 1)*3;
      // prefetch group g+2 into slot (g+2)%3 (wraps into next step's groups)
      {
        const int tg = g + 2;
        const unsigned char* bp = (tg < 18) ? Bc : Bn;
        const int rg = (tg < 18) ? tg : (tg - 18);
        const size_t off = (size_t)(rg >> 1)*49152 + (rg & 1)*3072;
#pragma unroll
        for (int q = 0; q < 3; ++q)
          bb[tg % 3][q] = *(const bf16x8*)(bp + off + q*1024);
      }
      if ((g & 1) == 0){
#pragma unroll
        for (int m = 0; m < 4; ++m){
          int addr = (m*16 + lr)*ROWB + ((ks*64 + lg*16) ^ ((lr & 7) << 4));
          af[m] = *(const bf16x8*)(A + addr);
        }
      }
      if (g < 2){       // ks==0: C = zf (no acc zero-init pass needed)
#pragma unroll
        for (int q = 0; q < 3; ++q)
#pragma unroll
          for (int m = 0; m < 4; ++m)
            acc[tb+q][m] = __builtin_amdgcn_mfma_f32_16x16x32_bf16(af[m], bb[g%3][q], zf, 0, 0, 0);
      } else {
#pragma unroll
        for (int q = 0; q < 3; ++q)
#pragma unroll
          for (int m = 0; m < 4; ++m)
            acc[tb+q][m] = __builtin_amdgcn_mfma_f32_16x16x32_bf16(af[m], bb[g%3][q], acc[tb+q][m], 0, 0, 0);
      }
      if (g == 17){
        // af holds ks=8 (aug) fragments (loaded at g==16); C = zf
#pragma unroll
        for (int m = 0; m < 4; ++m){
          accin[0][m] = __builtin_amdgcn_mfma_f32_16x16x32_bf16(af[m], bnin0, zf, 0, 0, 0);
          accin[1][m] = __builtin_amdgcn_mfma_f32_16x16x32_bf16(af[m], bnin1, zf, 0, 0, 0);
        }
      }
    }

    // ---- T14 issue-early: next-step input loads fly under the epilogue ----
    unsigned short vfeat = 0;
    unsigned vdf = 0;
    if (step < PHIST-1){
      vfeat = feat2[((size_t)(step+1)*8 + fx)*NBC + bc0 + seqx];
    } else if (step < PHIST + PFUT - 1){
      int s = step - (PHIST-1);
      if (fx < 8) vdf = dfeat[s*9 + fx];
    }

    // epilogue: gates (scales prefolded) + state update; h write merged in
#pragma unroll
    for (int m = 0; m < 4; ++m){
#pragma unroll
      for (int r = 0; r < 4; ++r){
        float h0 = __uint_as_float(hp[m][r] << 16);
        float h1 = __uint_as_float(hp[m][r] & 0xffff0000u);
        float rg0 = __builtin_amdgcn_rcpf(1.f + __builtin_amdgcn_exp2f(acc[0][m][r]));
        float rg1 = __builtin_amdgcn_rcpf(1.f + __builtin_amdgcn_exp2f(acc[1][m][r]));
        float zg0 = __builtin_amdgcn_rcpf(1.f + __builtin_amdgcn_exp2f(acc[2][m][r]));
        float zg1 = __builtin_amdgcn_rcpf(1.f + __builtin_amdgcn_exp2f(acc[3][m][r]));
        float n0 = fmaf(-2.f, __builtin_amdgcn_rcpf(1.f + __builtin_amdgcn_exp2f(
                       fmaf(rg0, acc[4][m][r], accin[0][m][r]))), 1.f);
        float n1 = fmaf(-2.f, __builtin_amdgcn_rcpf(1.f + __builtin_amdgcn_exp2f(
                       fmaf(rg1, acc[5][m][r], accin[1][m][r]))), 1.f);
        h0 = fmaf(zg0, h0 - n0, n0);
        h1 = fmaf(zg1, h1 - n1, n1);
        unsigned pk;
        asm("v_cvt_pk_bf16_f32 %0, %1, %2" : "=v"(pk) : "v"(h0), "v"(h1));
        hp[m][r] = pk;
        int seq = m*16 + lg*4 + r;
        *(unsigned*)(An + seq*ROWB + ((w*64 + lr*4) ^ ((seq & 7) << 4))) = pk;
      }
    }

    // ---- T14 write-late: stage next step's input section ----
    if (step < PHIST-1){
      *(unsigned short*)(An + seqx*ROWB + ((512 + fx*2) ^ ((seqx & 7) << 4))) = vfeat;
    } else if (step < PHIST + PFUT - 1){
      if (fx < 8)
        *(unsigned*)(An + seqx*ROWB + ((512 + fx*4) ^ ((seqx & 7) << 4))) = vdf;
      if (fx == 0)   // d=8 slot is the constant 1.0 column (bias lane)
        *(unsigned*)(An + seqx*ROWB + ((512 + 32) ^ ((seqx & 7) << 4))) = 0x00003F80u;
    }
    __syncthreads();   // single barrier per step

    // decoder head (unscaled Bhead); reads the parity just written
    if (!enc && w < 4){
      int s = step - PHIST;
      f32x4 ah = (f32x4){0.f,0.f,0.f,0.f};
#pragma unroll
      for (int ks = 0; ks < KSTEPS; ++ks){
        int addr = (w*16 + lr)*ROWB + ((ks*64 + lg*16) ^ ((lr & 7) << 4));
        bf16x8 afh = *(const bf16x8*)(An + addr);
        ah = __builtin_amdgcn_mfma_f32_16x16x32_bf16(afh, Bhead[(size_t)ks*64 + l], ah, 0, 0, 0);
      }
      if (lr < 4){
#pragma unroll
        for (int r = 0; r < 4; ++r){
          int seq = w*16 + lg*4 + r;
          int c = c0 + seq;
          float val = ah[r] + last_g[((size_t)b*4 + lr)*CC + c];
          pred[(((size_t)b*PFUT + s)*4 + lr)*CC + c] = val;
        }
      }
    }
  }
}

extern "C" void kernel_launch(void* const* d_in, const int* in_sizes, int n_in,
                              void* d_out, int out_size, void* d_ws, size_t ws_size,
                              hipStream_t stream)
{
  const float* x     = (const float*)d_in[0];
  const float* eWih  = (const float*)d_in[1];
  const float* eWhh  = (const float*)d_in[2];
  const float* ebih  = (const float*)d_in[3];
  const float* ebhh  = (const float*)d_in[4];
  const float* dWih  = (const float*)d_in[5];
  const float* dWhh  = (const float*)d_in[6];
  const float* dbih  = (const float*)d_in[7];
  const float* dbhh  = (const float*)d_in[8];
  const float* femb  = (const float*)d_in[9];
  const float* headW = (const float*)d_in[10];
  const float* headb = (const float*)d_in[11];

  char* ws = (char*)d_ws;
  unsigned short* BencU = (unsigned short*)(ws + OFF_BENC);
  unsigned short* BdecU = (unsigned short*)(ws + OFF_BDEC);
  unsigned short* BheadU= (unsigned short*)(ws + OFF_BHEAD);
  unsigned short* BninU = (unsigned short*)(ws + OFF_BNIN);
  unsigned* dfeat       = (unsigned*)(ws + OFF_DFEAT);
  unsigned short* feat2 = (unsigned short*)(ws + OFF_FEAT);
  float* last_g         = (float*)(ws + OFF_LAST);

  float* xnorm = (float*)d_out;
  float* pred  = (float*)d_out + (size_t)XNELEM;

  prep_kernel<<<227, 256, 0, stream>>>(eWih, eWhh, ebih, ebhh,
      dWih, dWhh, dbih, dbhh, femb, headW, headb,
      BencU, BdecU, BheadU, BninU, dfeat);
  stage_a_kernel<<<256, 128, 0, stream>>>(x, xnorm, feat2, last_g);
  gru_kernel<<<256, 512, 0, stream>>>(
      (const unsigned char*)BencU, (const unsigned char*)BdecU,
      (const bf16x8*)BheadU, (const bf16x8*)BninU,
      dfeat, feat2, last_g, pred);
}

// Round 12
// 349.242 us; speedup vs baseline: 2.1948x; 1.1573x over previous
//
#include <hip/hip_runtime.h>

// ---------------- problem constants ----------------
#define BB 32
#define TT 720
#define CC 512
#define PHIST 30
#define PFUT 14
#define PLEN 24
#define HID 256
#define NBC (BB*CC)          // 16384 sequences
#define XNELEM (BB*TT*CC)    // 11796480
#define KSTEPS 9             // K aug: 256 h + 32 aug = 288
#define ROWB 640             // LDS bytes per seq row (576 + pad for XOR swizzle)

// gate pre-scales folded into weights (prep):
//   r,z gates:  * -log2(e)  -> sigmoid(x) = rcp(1 + exp2(acc))
//   n gate:     * 2*log2(e) -> tanh(y)    = 1 - 2*rcp(1 + exp2(arg))
#define SIGM_SCALE (-1.44269504f)
#define TANH_SCALE ( 2.88539008f)

// ws layout (bytes)
#define OFF_BENC   0u           // ks-major: 9 ks * 48 tiles * 64 lanes * 16 B = 442368
#define OFF_BDEC   442368u
#define OFF_BHEAD  884736u      // 9*64*16 = 9216
#define OFF_BNIN   893952u      // 2 * 16 tiles * 64 lanes * 16 B = 32768 (enc, dec)
#define OFF_DFEAT  926720u      // 14*9*4 = 504 (padded 512)
#define OFF_FEAT   927232u      // 30*8*16384*2 = 7864320
#define OFF_LAST   8791552u     // 32*4*512*4 = 262144

typedef short bf16x8 __attribute__((ext_vector_type(8)));
typedef float f32x4 __attribute__((ext_vector_type(4)));

__device__ __forceinline__ unsigned short f2bf(float f){
  unsigned u = __float_as_uint(f);
  u = (u + 0x7fffu + ((u >> 16) & 1u)) >> 16;
  return (unsigned short)u;
}

// h-column K-permutation: k = wv*32 + lr*2 + jt  <->  n = wv*32 + jt*16 + lr
__device__ __forceinline__ int nh_of_k(int k){
  return (k & 0xE0) | ((k & 1) << 4) | ((k >> 1) & 15);
}

// ---------------- prep: pack weights into MFMA B-fragment order ----------------
// Benc/Bdec ks-major: [ks][tile(=wv*6+t6)][lane][8 bf16], gate scales prefolded.
__global__ void prep_kernel(
    const float* __restrict__ eWih, const float* __restrict__ eWhh,
    const float* __restrict__ ebih, const float* __restrict__ ebhh,
    const float* __restrict__ dWih, const float* __restrict__ dWhh,
    const float* __restrict__ dbih, const float* __restrict__ dbhh,
    const float* __restrict__ femb, const float* __restrict__ headW,
    const float* __restrict__ headb,
    unsigned short* __restrict__ Benc, unsigned short* __restrict__ Bdec,
    unsigned short* __restrict__ Bhead, unsigned short* __restrict__ Bnin,
    unsigned* __restrict__ dfeat)
{
  const int NE = 48*9*64; // 27648
  int id = blockIdx.x*256 + threadIdx.x;
  if (id < 2*NE){
    bool isenc = id < NE;
    int s = isenc ? id : id - NE;
    int g = s / 576, rem = s % 576, ks = rem / 64, lane = rem % 64;
    int wv = g / 6, t6 = g % 6;
    int n = (t6 >> 1)*256 + wv*32 + (t6 & 1)*16 + (lane & 15);
    int kb = ks*32 + (lane >> 4)*8;
    unsigned short* outp = (isenc ? Benc : Bdec) + ((size_t)((ks*48 + g)*64 + lane))*8;
    const float* Whh = isenc ? eWhh : dWhh;
    const float* Wih = isenc ? eWih : dWih;
    const float* bih = isenc ? ebih : dbih;
    const float* bhh = isenc ? ebhh : dbhh;
    const int FN = isenc ? 7 : 16;
    const int KC = 256 + FN;
    const float sc = (n < 512) ? SIGM_SCALE : TANH_SCALE;
    for (int e = 0; e < 8; ++e){
      int k = kb + e;
      float v;
      if (k < 256)            v = Whh[n*256 + nh_of_k(k)];
      else if (n < 512){      // r,z gates: input part + fused bias column
        if (k < KC)           v = Wih[n*FN + (k - 256)];
        else if (k == KC)     v = bih[n] + bhh[n];
        else                  v = 0.f;
      } else {                // n gate: only hidden bias (input part in Bnin)
        v = (k == KC) ? bhh[n] : 0.f;
      }
      outp[e] = f2bf(v*sc);
    }
  } else if (id < 2*NE + 576){
    int s = id - 2*NE;
    int ks = s / 64, lane = s % 64;
    int o = lane & 15, kb = ks*32 + (lane >> 4)*8;
    unsigned short* outp = Bhead + (size_t)s*8;
    for (int e = 0; e < 8; ++e){
      int k = kb + e;
      float v = 0.f;
      if (o < 4){
        if (k < 256)       v = headW[o*256 + nh_of_k(k)];
        else if (k == 272) v = headb[o];
      }
      outp[e] = f2bf(v);
    }
  } else if (id < 2*NE + 576 + 2048){
    // Bnin: i_n input-part tiles (n gate -> TANH_SCALE prefolded)
    int s3 = id - (2*NE + 576);
    int ed = s3 >> 10, rem = s3 & 1023;
    int wv = rem >> 7, jt = (rem >> 6) & 1, lane = rem & 63;
    int n = 512 + wv*32 + jt*16 + (lane & 15);
    unsigned short* outp = Bnin + (size_t)ed*8192 + (size_t)(((wv*2 + jt)*64) + lane)*8;
    const int FN = ed ? 16 : 7;
    const float* Wih = ed ? dWih : eWih;
    const float* bih = ed ? dbih : ebih;
    for (int e = 0; e < 8; ++e){
      int kk = (lane >> 4)*8 + e;
      float v;
      if (kk < FN)       v = Wih[n*FN + kk];
      else if (kk == FN) v = bih[n];
      else               v = 0.f;
      outp[e] = f2bf(v*TANH_SCALE);
    }
  } else if (id < 2*NE + 576 + 2048 + PFUT*9){
    int s2 = id - (2*NE + 576 + 2048);
    int st = s2 / 9, d = s2 % 9;
    unsigned v;
    if (d < 8) v = (unsigned)f2bf(femb[st*16 + 2*d]) | ((unsigned)f2bf(femb[st*16 + 2*d + 1]) << 16);
    else       v = (unsigned)f2bf(1.0f);
    dfeat[s2] = v;
  }
}

// ---------------- stage A: SWT + stats + features + x_norm ----------------
// 384 threads/block: 64 bc-columns x 6 patch-sixths (5 patches each).
__global__ __launch_bounds__(384,2) void stage_a_kernel(
    const float* __restrict__ x, float* __restrict__ xnorm,
    unsigned short* __restrict__ feat2, float* __restrict__ last_g)
{
  __shared__ float sG[6][2][64];
  const int tid = threadIdx.x, lane = tid & 63, half = tid >> 6;  // half in [0,6)
  const int bc = blockIdx.x*64 + lane;
  const int b = bc >> 9, c = bc & 511;
  const float* xp = x + (size_t)b*TT*CC + c;
  float* op = xnorm + (size_t)b*TT*CC + c;
  float gsum = 0.f, gss = 0.f;
  float lastv[4] = {0,0,0,0};
  const float inv24 = 1.f/24.f, inv23 = 1.f/23.f;
  const int p0 = half*5, p1 = p0 + 5;

  for (int p = p0; p < p1; ++p){
    const int t0 = p*PLEN;
    float xl[31];
#pragma unroll
    for (int i = 0; i < 31; ++i){
      int t = t0 - 4 + i;
      t = (t < 0) ? -t : ((t >= TT) ? (2*TT - 2 - t) : t);
      xl[i] = xp[(size_t)t*CC];
    }
    float a1l[30];
#pragma unroll
    for (int j = 0; j < 30; ++j) a1l[j] = 0.5f*(xl[j] + xl[j+1]);
    if (p == 0){ a1l[2] = a1l[4]; a1l[1] = a1l[5]; a1l[0] = a1l[6]; }
    if (p == PHIST-1){ a1l[27] = a1l[25]; a1l[28] = a1l[24]; a1l[29] = a1l[23]; }
    float a2l[28];
#pragma unroll
    for (int m = 0; m < 28; ++m) a2l[m] = 0.5f*(a1l[m] + a1l[m+2]);
    if (p == 0){ a2l[1] = a2l[3]; a2l[0] = a2l[4]; }
    if (p == PHIST-1){ a2l[26] = a2l[24]; a2l[27] = a2l[23]; }
    float a3l[24], d1l[24], d2l[24], d3l[24];
    float sL=0, sL2=0, s2=0, s22=0, s3=0, s32=0, sH2=0;
#pragma unroll
    for (int n = 0; n < 24; ++n){
      float a3 = 0.5f*(a2l[n] + a2l[n+4]);
      float d1 = xl[n+4] - a1l[n+3];
      float d2 = a1l[n+3] - a2l[n+2];
      float d3 = a2l[n+2] - a3;
      a3l[n]=a3; d1l[n]=d1; d2l[n]=d2; d3l[n]=d3;
      sL += a3; sL2 += a3*a3;
      s2 += d2; s22 += d2*d2;
      s3 += d3; s32 += d3*d3;
      sH2 += d1*d1;
      gsum += a3; gss += a3*a3;
    }
    float mu   = sL*inv24;
    float sigL = fmaxf(sqrtf(fmaxf((sL2 - sL*sL*inv24)*inv23, 0.f)), 1e-3f);
    float sig2 = fmaxf(sqrtf(fmaxf((s22 - s2*s2*inv24)*inv23, 0.f)), 1e-3f);
    float sig3 = fmaxf(sqrtf(fmaxf((s32 - s3*s3*inv24)*inv23, 0.f)), 1e-3f);
    float EL = sL2*inv24, E2 = s22*inv24, E3 = s32*inv24, EH = sH2*inv24;
    float rho = EH / (EL + EH + E2 + E3 + 1e-6f);
    float lsl = __logf(sigL), ls2 = __logf(sig2), ls3 = __logf(sig3);
    size_t fb = ((size_t)p*8)*NBC + bc;
    feat2[fb + 0*NBC] = f2bf(mu);
    feat2[fb + 1*NBC] = f2bf(lsl);
    feat2[fb + 2*NBC] = f2bf(ls2);
    feat2[fb + 3*NBC] = f2bf(ls3);
    feat2[fb + 4*NBC] = f2bf(rho);
    if (p == PHIST-1){ lastv[0]=mu; lastv[1]=lsl; lastv[2]=ls2; lastv[3]=ls3; }
    float iL = 1.f/sigL, i2 = 1.f/sig2, i3 = 1.f/sig3;
#pragma unroll
    for (int n = 0; n < 24; ++n){
      float v = (a3l[n]-mu)*iL + d1l[n] + d2l[n]*i2 + d3l[n]*i3;
      op[(size_t)(t0+n)*CC] = v;
    }
  }
  sG[half][0][lane] = gsum; sG[half][1][lane] = gss;
  __syncthreads();
  float gs = 0.f, g2 = 0.f;
#pragma unroll
  for (int i = 0; i < 6; ++i){ gs += sG[i][0][lane]; g2 += sG[i][1][lane]; }
  float mug  = gs*(1.f/720.f);
  float sigg = fmaxf(sqrtf(fmaxf((g2 - gs*gs*(1.f/720.f))*(1.f/719.f), 0.f)), 1e-3f);
  unsigned short f5 = f2bf(mug), f6 = f2bf(__logf(sigg)), f7 = f2bf(1.0f);
  for (int p = p0; p < p1; ++p){
    size_t fb = ((size_t)p*8)*NBC + bc;
    feat2[fb + 5*NBC] = f5;
    feat2[fb + 6*NBC] = f6;
    feat2[fb + 7*NBC] = f7;
  }
  if (half == 5){
#pragma unroll
    for (int o = 0; o < 4; ++o) last_g[((size_t)b*4 + o)*CC + c] = lastv[o];
  }
}

// ---------------- GRU: encoder 30 + decoder 14 + fused head ----------------
// R11 structure unchanged: 256 blocks x 512 thr, 3-slot half-kstep ring,
// Ab[2] 1-barrier, prefolded gate scales, zf C-operand, cvt_pk h-pack,
// T14 issue-early/write-late feature staging.
__global__ __launch_bounds__(512,2) void gru_kernel(
    const unsigned char* __restrict__ BencB, const unsigned char* __restrict__ BdecB,
    const bf16x8* __restrict__ Bhead, const bf16x8* __restrict__ BninP,
    const unsigned* __restrict__ dfeat,       // [14][9] packed dec A-aug dwords
    const unsigned short* __restrict__ feat2, // [30][8][16384] bf16
    const float* __restrict__ last_g,         // [32][4][512]
    float* __restrict__ pred)                 // [32][14][4][512]
{
  __shared__ unsigned char Ab[2][64*ROWB];    // 2 x 40960
  const int tid = threadIdx.x;
  const int w = tid >> 6, l = tid & 63, lr = l & 15, lg = l >> 4;
  const int bc0 = blockIdx.x * 64;
  const int b = bc0 >> 9, c0 = bc0 & 511;

  for (int i = tid; i < 2*64*ROWB/4; i += 512) ((unsigned*)Ab)[i] = 0u;

  // per-wave B base pointers (ks-major; wave's 6 tiles contiguous per ks)
  const unsigned char* Bwe = BencB + (size_t)(w*6*64 + l)*16;
  const unsigned char* Bwd = BdecB + (size_t)(w*6*64 + l)*16;

  // i_n input-part tiles (resident; swapped at decoder start)
  bf16x8 bnin0 = BninP[(size_t)(w*2 + 0)*64 + l];
  bf16x8 bnin1 = BninP[(size_t)(w*2 + 1)*64 + l];

  // packed h state: bf16 pair (jt0 | jt1<<16) per (m, r)
  unsigned hp[4][4];
#pragma unroll
  for (int m=0;m<4;m++)
#pragma unroll
    for (int r=0;r<4;r++) hp[m][r] = 0u;

  const f32x4 zf = {0.f, 0.f, 0.f, 0.f};   // loop-invariant zero C-operand

  // B ring: 3 slots x 3 tiles; preload groups 0,1 of step 0 (ks0 halves 0,1)
  bf16x8 bb[3][3];
#pragma unroll
  for (int q=0;q<3;q++){
    bb[0][q] = *(const bf16x8*)(Bwe + q*1024);
    bb[1][q] = *(const bf16x8*)(Bwe + 3072 + q*1024);
  }

  const int seqx = tid & 63, fx = tid >> 6;

  __syncthreads();
  { // stage encoder features for step 0 into parity 0
    unsigned short v = feat2[((size_t)0*8 + fx)*NBC + bc0 + seqx];
    *(unsigned short*)(Ab[0] + seqx*ROWB + ((512 + fx*2) ^ ((seqx & 7) << 4))) = v;
  }
  __syncthreads();

  for (int step = 0; step < PHIST + PFUT; ++step){
    const bool enc = step < PHIST;
    const int sp = step & 1;
    const unsigned char* A  = Ab[sp];
    unsigned char*       An = Ab[sp^1];
    const unsigned char* Bc = enc ? Bwe : Bwd;
    const unsigned char* Bn = (step == PHIST-1) ? Bwd :
                              ((step >= PHIST+PFUT-1) ? Bwe : Bc);
    if (step == PHIST){
      bnin0 = BninP[1024 + (size_t)(w*2 + 0)*64 + l];
      bnin1 = BninP[1024 + (size_t)(w*2 + 1)*64 + l];
    }

    f32x4 acc[6][4];
    f32x4 accin[2][4];

    bf16x8 af[4];
#pragma unroll
    for (int g = 0; g < 18; ++g){
      const int ks = g >> 1, tb = (g & 1)*3;
      // prefetch group g+2 into slot (g+2)%3 (wraps into next step's groups)
      {
        const int tg = g + 2;
        const unsigned char* bp = (tg < 18) ? Bc : Bn;
        const int rg = (tg < 18) ? tg : (tg - 18);
        const size_t off = (size_t)(rg >> 1)*49152 + (rg & 1)*3072;
#pragma unroll
        for (int q = 0; q < 3; ++q)
          bb[tg % 3][q] = *(const bf16x8*)(bp + off + q*1024);
      }
      if ((g & 1) == 0){
#pragma unroll
        for (int m = 0; m < 4; ++m){
          int addr = (m*16 + lr)*ROWB + ((ks*64 + lg*16) ^ ((lr & 7) << 4));
          af[m] = *(const bf16x8*)(A + addr);
        }
      }
      if (g < 2){       // ks==0: C = zf (no acc zero-init pass needed)
#pragma unroll
        for (int q = 0; q < 3; ++q)
#pragma unroll
          for (int m = 0; m < 4; ++m)
            acc[tb+q][m] = __builtin_amdgcn_mfma_f32_16x16x32_bf16(af[m], bb[g%3][q], zf, 0, 0, 0);
      } else {
#pragma unroll
        for (int q = 0; q < 3; ++q)
#pragma unroll
          for (int m = 0; m < 4; ++m)
            acc[tb+q][m] = __builtin_amdgcn_mfma_f32_16x16x32_bf16(af[m], bb[g%3][q], acc[tb+q][m], 0, 0, 0);
      }
      if (g == 17){
        // af holds ks=8 (aug) fragments (loaded at g==16); C = zf
#pragma unroll
        for (int m = 0; m < 4; ++m){
          accin[0][m] = __builtin_amdgcn_mfma_f32_16x16x32_bf16(af[m], bnin0, zf, 0, 0, 0);
          accin[1][m] = __builtin_amdgcn_mfma_f32_16x16x32_bf16(af[m], bnin1, zf, 0, 0, 0);
        }
      }
    }

    // ---- T14 issue-early: next-step input loads fly under the epilogue ----
    unsigned short vfeat = 0;
    unsigned vdf = 0;
    if (step < PHIST-1){
      vfeat = feat2[((size_t)(step+1)*8 + fx)*NBC + bc0 + seqx];
    } else if (step < PHIST + PFUT - 1){
      int s = step - (PHIST-1);
      if (fx < 8) vdf = dfeat[s*9 + fx];
    }

    // epilogue: gates (scales prefolded) + state update; h write merged in
#pragma unroll
    for (int m = 0; m < 4; ++m){
#pragma unroll
      for (int r = 0; r < 4; ++r){
        float h0 = __uint_as_float(hp[m][r] << 16);
        float h1 = __uint_as_float(hp[m][r] & 0xffff0000u);
        float rg0 = __builtin_amdgcn_rcpf(1.f + __builtin_amdgcn_exp2f(acc[0][m][r]));
        float rg1 = __builtin_amdgcn_rcpf(1.f + __builtin_amdgcn_exp2f(acc[1][m][r]));
        float zg0 = __builtin_amdgcn_rcpf(1.f + __builtin_amdgcn_exp2f(acc[2][m][r]));
        float zg1 = __builtin_amdgcn_rcpf(1.f + __builtin_amdgcn_exp2f(acc[3][m][r]));
        float n0 = fmaf(-2.f, __builtin_amdgcn_rcpf(1.f + __builtin_amdgcn_exp2f(
                       fmaf(rg0, acc[4][m][r], accin[0][m][r]))), 1.f);
        float n1 = fmaf(-2.f, __builtin_amdgcn_rcpf(1.f + __builtin_amdgcn_exp2f(
                       fmaf(rg1, acc[5][m][r], accin[1][m][r]))), 1.f);
        h0 = fmaf(zg0, h0 - n0, n0);
        h1 = fmaf(zg1, h1 - n1, n1);
        unsigned pk;
        asm("v_cvt_pk_bf16_f32 %0, %1, %2" : "=v"(pk) : "v"(h0), "v"(h1));
        hp[m][r] = pk;
        int seq = m*16 + lg*4 + r;
        *(unsigned*)(An + seq*ROWB + ((w*64 + lr*4) ^ ((seq & 7) << 4))) = pk;
      }
    }

    // ---- T14 write-late: stage next step's input section ----
    if (step < PHIST-1){
      *(unsigned short*)(An + seqx*ROWB + ((512 + fx*2) ^ ((seqx & 7) << 4))) = vfeat;
    } else if (step < PHIST + PFUT - 1){
      if (fx < 8)
        *(unsigned*)(An + seqx*ROWB + ((512 + fx*4) ^ ((seqx & 7) << 4))) = vdf;
      if (fx == 0)   // d=8 slot is the constant 1.0 column (bias lane)
        *(unsigned*)(An + seqx*ROWB + ((512 + 32) ^ ((seqx & 7) << 4))) = 0x00003F80u;
    }
    __syncthreads();   // single barrier per step

    // decoder head (unscaled Bhead); reads the parity just written
    if (!enc && w < 4){
      int s = step - PHIST;
      f32x4 ah = (f32x4){0.f,0.f,0.f,0.f};
#pragma unroll
      for (int ks = 0; ks < KSTEPS; ++ks){
        int addr = (w*16 + lr)*ROWB + ((ks*64 + lg*16) ^ ((lr & 7) << 4));
        bf16x8 afh = *(const bf16x8*)(An + addr);
        ah = __builtin_amdgcn_mfma_f32_16x16x32_bf16(afh, Bhead[(size_t)ks*64 + l], ah, 0, 0, 0);
      }
      if (lr < 4){
#pragma unroll
        for (int r = 0; r < 4; ++r){
          int seq = w*16 + lg*4 + r;
          int c = c0 + seq;
          float val = ah[r] + last_g[((size_t)b*4 + lr)*CC + c];
          pred[(((size_t)b*PFUT + s)*4 + lr)*CC + c] = val;
        }
      }
    }
  }
}

extern "C" void kernel_launch(void* const* d_in, const int* in_sizes, int n_in,
                              void* d_out, int out_size, void* d_ws, size_t ws_size,
                              hipStream_t stream)
{
  const float* x     = (const float*)d_in[0];
  const float* eWih  = (const float*)d_in[1];
  const float* eWhh  = (const float*)d_in[2];
  const float* ebih  = (const float*)d_in[3];
  const float* ebhh  = (const float*)d_in[4];
  const float* dWih  = (const float*)d_in[5];
  const float* dWhh  = (const float*)d_in[6];
  const float* dbih  = (const float*)d_in[7];
  const float* dbhh  = (const float*)d_in[8];
  const float* femb  = (const float*)d_in[9];
  const float* headW = (const float*)d_in[10];
  const float* headb = (const float*)d_in[11];

  char* ws = (char*)d_ws;
  unsigned short* BencU = (unsigned short*)(ws + OFF_BENC);
  unsigned short* BdecU = (unsigned short*)(ws + OFF_BDEC);
  unsigned short* BheadU= (unsigned short*)(ws + OFF_BHEAD);
  unsigned short* BninU = (unsigned short*)(ws + OFF_BNIN);
  unsigned* dfeat       = (unsigned*)(ws + OFF_DFEAT);
  unsigned short* feat2 = (unsigned short*)(ws + OFF_FEAT);
  float* last_g         = (float*)(ws + OFF_LAST);

  float* xnorm = (float*)d_out;
  float* pred  = (float*)d_out + (size_t)XNELEM;

  prep_kernel<<<227, 256, 0, stream>>>(eWih, eWhh, ebih, ebhh,
      dWih, dWhh, dbih, dbhh, femb, headW, headb,
      BencU, BdecU, BheadU, BninU, dfeat);
  stage_a_kernel<<<256, 384, 0, stream>>>(x, xnorm, feat2, last_g);
  gru_kernel<<<256, 512, 0, stream>>>(
      (const unsigned char*)BencU, (const unsigned char*)BdecU,
      (const bf16x8*)BheadU, (const bf16x8*)BninU,
      dfeat, feat2, last_g, pred);
}